// Round 2
// baseline (460.937 us; speedup 1.0000x reference)
//
#include <hip/hip_runtime.h>
#include <stdint.h>

// ---------------- problem constants ----------------
#define GN   33
#define GG   1089      // 33*33
#define GGG  35937     // 33^3
#define BATCH 4
#define KK   8
#define RR   8
#define HLR  256
#define WLR  256
#define HFULL 1080
#define WFULL 1920
#define NPIX (HFULL*WFULL)          // 2,073,600 per channel
#define NPIX4 (NPIX/4)              // 518,400 float4 per channel

// d_out layout (floats): out | alpha | delta | L | delta_norm
#define OUT_ALPHA 24883200
#define OUT_DELTA 24883232
#define OUT_L     25314476
#define OUT_DNORM 25745720

// ---------------- workspace layout (float offsets) ----------------
// Phase A (convs): h1 buffers at 0 / 1,048,576 (4 MB each).
// Phase B (pack+apply): 64B-entry LUT overlays bytes [0, 9,199,872) — safe,
// pack runs after conv2 has fully consumed h1 (stream-ordered).
#define WS_H1WP   0          // 4*16*128*128 floats
#define WS_H1RP   1048576
#define WS_LUT64B 0          // byte offset of 64B-entry LUT (4*35937*64 B)
#define WS_STATS  2400000    // beyond LUT64 end (2,299,968 floats)
#define WS_MEANWP 2400000    // 128
#define WS_MEANRP 2400128    // 128
#define WS_DNORM  2400256    // 1
#define WS_ALPHA  2400260    // 32
#define WS_U      2400292    // 4*264
#define WS_V      2401348
#define WS_W      2402404
#define WS_C      2403460    // 4*24  (end ~2,403,556 floats = 9.62 MB)

__device__ __forceinline__ unsigned short f2bf(float f) {
    unsigned u = __float_as_uint(f);
    unsigned r = (u + 0x7fffu + ((u >> 16) & 1u)) >> 16;
    return (unsigned short)r;
}
__device__ __forceinline__ float bflo(unsigned u) { return __uint_as_float(u << 16); }
__device__ __forceinline__ float bfhi(unsigned u) { return __uint_as_float(u & 0xffff0000u); }

// ---------------- conv1: 3->16 ch, 3x3 s2 p1, relu (LDS-tiled, all-o per thread) ----------------
#define C1_W 260
__global__ __launch_bounds__(256) void conv1_kernel(
    const float* __restrict__ img,
    const float* __restrict__ w_wp, const float* __restrict__ b_wp,
    const float* __restrict__ w_rp, const float* __restrict__ b_rp,
    float* __restrict__ ws)
{
    const int enc = blockIdx.z;
    const float* w  = enc ? w_rp : w_wp;
    const float* bb = enc ? b_rp : b_wp;
    float* out = ws + (enc ? WS_H1RP : WS_H1WP);
    const int b  = blockIdx.y;
    const int t0 = blockIdx.x;               // out rows 2t0, 2t0+1
    __shared__ float tile[3][5][C1_W];       // in rows 2t0-1..2t0+3, cols -1..255 (col 0 = global -1)
    const float* imb = img + (size_t)b * 3 * HLR * WLR;
    for (int l = threadIdx.x; l < 3 * 5 * C1_W; l += 256) {
        const int c  = l / (5 * C1_W);
        const int rem = l - c * (5 * C1_W);
        const int rw = rem / C1_W, cl = rem - rw * C1_W;
        const int gr = 2 * t0 - 1 + rw;
        const int gc = cl - 1;
        float v = 0.f;
        if (cl < 257 && (unsigned)gr < 256u && (unsigned)gc < 256u)
            v = imb[(c * HLR + gr) * WLR + gc];
        ((float*)tile)[l] = v;
    }
    __syncthreads();
    const int r = threadIdx.x >> 7, j = threadIdx.x & 127;
    float acc[16];
    #pragma unroll
    for (int o = 0; o < 16; ++o) acc[o] = bb[o];
    #pragma unroll
    for (int c = 0; c < 3; ++c)
        #pragma unroll
        for (int ky = 0; ky < 3; ++ky)
            #pragma unroll
            for (int kx = 0; kx < 3; ++kx) {
                const float v = tile[c][2 * r + ky][2 * j + kx];
                const float* wk = w + c * 9 + ky * 3 + kx;
                #pragma unroll
                for (int o = 0; o < 16; ++o)
                    acc[o] += wk[o * 27] * v;
            }
    const int prow = 2 * t0 + r;
    #pragma unroll
    for (int o = 0; o < 16; ++o)
        out[((b * 16 + o) << 14) + prow * 128 + j] = fmaxf(acc[o], 0.f);
}

// ---------------- conv2: 16->32 ch, 3x3 s2 p1, relu + mean (LDS-tiled, all-o per thread) ----------------
#define C2_W 132
__global__ __launch_bounds__(256) void conv2_kernel(
    const float* __restrict__ w_wp, const float* __restrict__ b_wp,
    const float* __restrict__ w_rp, const float* __restrict__ b_rp,
    float* __restrict__ ws)
{
    const int enc = blockIdx.z;
    const float* w  = enc ? w_rp : w_wp;
    const float* bb = enc ? b_rp : b_wp;
    const float* h1 = ws + (enc ? WS_H1RP : WS_H1WP) + ((size_t)blockIdx.y << 18); // b*16*16384
    float* mean = ws + (enc ? WS_MEANRP : WS_MEANWP) + blockIdx.y * 32;
    const int t0 = blockIdx.x;               // out rows 4t0..4t0+3 (16 tiles)
    __shared__ float tile[4][9][C2_W];       // 4 chans, in rows 8t0-1..8t0+7, cols -1..127
    const int di = threadIdx.x >> 6, j = threadIdx.x & 63;
    float acc[32];
    #pragma unroll
    for (int o = 0; o < 32; ++o) acc[o] = bb[o];
    for (int cb = 0; cb < 16; cb += 4) {
        __syncthreads();
        for (int l = threadIdx.x; l < 4 * 9 * C2_W; l += 256) {
            const int cc = l / (9 * C2_W);
            const int rem = l - cc * (9 * C2_W);
            const int rw = rem / C2_W, cl = rem - rw * C2_W;
            const int gr = 8 * t0 - 1 + rw;
            const int gc = cl - 1;
            float v = 0.f;
            if (cl < 129 && (unsigned)gr < 128u && (unsigned)gc < 128u)
                v = h1[((cb + cc) << 14) + gr * 128 + gc];
            ((float*)tile)[l] = v;
        }
        __syncthreads();
        #pragma unroll
        for (int cc = 0; cc < 4; ++cc) {
            float vv[9];
            #pragma unroll
            for (int ky = 0; ky < 3; ++ky)
                #pragma unroll
                for (int kx = 0; kx < 3; ++kx)
                    vv[ky * 3 + kx] = tile[cc][2 * di + ky][2 * j + kx];
            const float* wc = w + (cb + cc) * 9;
            #pragma unroll
            for (int o = 0; o < 32; ++o) {
                const float* wo = wc + o * 144;
                #pragma unroll
                for (int kk = 0; kk < 9; ++kk)
                    acc[o] += wo[kk] * vv[kk];
            }
        }
    }
    // relu + wave-reduce + atomic accumulate into mean[o] (sum; head divides by 4096)
    const int lane = threadIdx.x & 63;
    #pragma unroll
    for (int o = 0; o < 32; ++o) {
        float v = fmaxf(acc[o], 0.f);
        #pragma unroll
        for (int off = 32; off; off >>= 1) v += __shfl_down(v, off);
        if (!lane) atomicAdd(&mean[o], v);
    }
}

// ---------------- heads: alpha, u, v, w, c ----------------
__global__ __launch_bounds__(256) void head_kernel(
    const float* __restrict__ wp_fc_w, const float* __restrict__ wp_fc_b,
    const float* __restrict__ fcu_w, const float* __restrict__ fcu_b,
    const float* __restrict__ fcv_w, const float* __restrict__ fcv_b,
    const float* __restrict__ fcw_w, const float* __restrict__ fcw_b,
    const float* __restrict__ fcc_w, const float* __restrict__ fcc_b,
    float* __restrict__ ws, float* __restrict__ dout)
{
    const int it = blockIdx.x * 256 + threadIdx.x;
    if (it >= BATCH * 824) return;
    const int b = it / 824, j = it - b * 824;
    const float msc = 1.0f / 4096.0f;
    const float* mw = ws + WS_MEANWP + b * 32;
    const float* mr = ws + WS_MEANRP + b * 32;
    if (j < 8) {
        const float* row = wp_fc_w + j * 32;
        float acc = wp_fc_b[j];
        #pragma unroll 8
        for (int q = 0; q < 32; ++q) acc += row[q] * (mw[q] * msc);
        ws[WS_ALPHA + b * 8 + j] = acc;
        dout[OUT_ALPHA + b * 8 + j] = acc;
    } else if (j < 272) {
        const int jj = j - 8;
        const float* row = fcu_w + jj * 32;
        float acc = fcu_b[jj];
        #pragma unroll 8
        for (int q = 0; q < 32; ++q) acc += row[q] * (mr[q] * msc);
        ws[WS_U + b * 264 + jj] = acc;
    } else if (j < 536) {
        const int jj = j - 272;
        const float* row = fcv_w + jj * 32;
        float acc = fcv_b[jj];
        #pragma unroll 8
        for (int q = 0; q < 32; ++q) acc += row[q] * (mr[q] * msc);
        ws[WS_V + b * 264 + jj] = acc;
    } else if (j < 800) {
        const int jj = j - 536;
        const float* row = fcw_w + jj * 32;
        float acc = fcw_b[jj];
        #pragma unroll 8
        for (int q = 0; q < 32; ++q) acc += row[q] * (mr[q] * msc);
        ws[WS_W + b * 264 + jj] = acc;
    } else {
        const int jj = j - 800;
        const float* row = fcc_w + jj * 32;
        float acc = fcc_b[jj];
        #pragma unroll 8
        for (int q = 0; q < 32; ++q) acc += row[q] * (mr[q] * msc);
        ws[WS_C + b * 24 + jj] = acc;
    }
}

// ---------------- LUT build: delta, L (f32 to d_out), |delta| sum ----------------
__global__ __launch_bounds__(256) void lut_build_kernel(
    const float* __restrict__ bases,
    float* __restrict__ ws, float* __restrict__ dout)
{
    const int tid = blockIdx.x * 256 + threadIdx.x;
    float sum3 = 0.f;
    if (tid < BATCH * GGG) {
        const int b = tid / GGG, s = tid - b * GGG;
        const int x = s / GG;
        const int rem = s - x * GG;
        const int y = rem / GN, z = rem - y * GN;
        const float* U = ws + WS_U + b * 264;
        const float* V = ws + WS_V + b * 264;
        const float* W = ws + WS_W + b * 264;
        const float* C = ws + WS_C + b * 24;
        const float* A = ws + WS_ALPHA + b * 8;
        float d0 = 0.f, d1 = 0.f, d2 = 0.f;
        #pragma unroll
        for (int r = 0; r < RR; ++r) {
            const float t = U[r * GN + x] * V[r * GN + y] * W[r * GN + z];
            d0 += t * C[r * 3 + 0];
            d1 += t * C[r * 3 + 1];
            d2 += t * C[r * 3 + 2];
        }
        float l0 = d0, l1 = d1, l2 = d2;
        #pragma unroll
        for (int k = 0; k < KK; ++k) {
            const float a = A[k];
            const float* bp = bases + ((size_t)k * GGG + s) * 3;
            l0 += a * bp[0];
            l1 += a * bp[1];
            l2 += a * bp[2];
        }
        const size_t o3 = (size_t)tid * 3;
        dout[OUT_DELTA + o3 + 0] = d0;
        dout[OUT_DELTA + o3 + 1] = d1;
        dout[OUT_DELTA + o3 + 2] = d2;
        dout[OUT_L + o3 + 0] = l0;
        dout[OUT_L + o3 + 1] = l1;
        dout[OUT_L + o3 + 2] = l2;
        sum3 = fabsf(d0) + fabsf(d1) + fabsf(d2);
    }
    #pragma unroll
    for (int off = 32; off; off >>= 1) sum3 += __shfl_down(sum3, off);
    __shared__ float s4[4];
    const int lane = threadIdx.x & 63, wid = threadIdx.x >> 6;
    if (!lane) s4[wid] = sum3;
    __syncthreads();
    if (!threadIdx.x) atomicAdd(ws + WS_DNORM, s4[0] + s4[1] + s4[2] + s4[3]);
}

__global__ void dnorm_kernel(const float* __restrict__ ws, float* __restrict__ dout)
{
    dout[OUT_DNORM] = ws[WS_DNORM] * (1.0f / (float)(BATCH * GGG * 3));
}

// ---------------- pack: 64B entry = 8 corners, SoA bf16 per channel ----------------
// entry s=(x*33+y)*33+z: ushort[32] = { r[k=0..7], g[k], b[k], pad } with k = cx*4+cy*2+cz
__global__ __launch_bounds__(256) void pack_kernel(
    const float* __restrict__ dout, float* __restrict__ ws)
{
    const int tid = blockIdx.x * 256 + threadIdx.x;
    if (tid >= BATCH * GGG) return;
    const int b = tid / GGG, s = tid - b * GGG;
    const int x = s / GG;
    const int rem = s - x * GG;
    const int y = rem / GN, z = rem - y * GN;
    const int x1 = min(x + 1, GN - 1), y1 = min(y + 1, GN - 1), z1 = min(z + 1, GN - 1);
    const float* Lb = dout + OUT_L + (size_t)b * GGG * 3;
    int off[8];
    off[0] = ((x  * GN + y ) * GN + z ) * 3;
    off[1] = ((x  * GN + y ) * GN + z1) * 3;
    off[2] = ((x  * GN + y1) * GN + z ) * 3;
    off[3] = ((x  * GN + y1) * GN + z1) * 3;
    off[4] = ((x1 * GN + y ) * GN + z ) * 3;
    off[5] = ((x1 * GN + y ) * GN + z1) * 3;
    off[6] = ((x1 * GN + y1) * GN + z ) * 3;
    off[7] = ((x1 * GN + y1) * GN + z1) * 3;
    unsigned short rr[8], gg[8], bb[8];
    #pragma unroll
    for (int k = 0; k < 8; ++k) {
        rr[k] = f2bf(Lb[off[k] + 0]);
        gg[k] = f2bf(Lb[off[k] + 1]);
        bb[k] = f2bf(Lb[off[k] + 2]);
    }
    uint4* dst = (uint4*)((char*)ws + WS_LUT64B) + (size_t)tid * 4;
    uint4 wr, wg, wb;
    wr.x = (unsigned)rr[0] | ((unsigned)rr[1] << 16);
    wr.y = (unsigned)rr[2] | ((unsigned)rr[3] << 16);
    wr.z = (unsigned)rr[4] | ((unsigned)rr[5] << 16);
    wr.w = (unsigned)rr[6] | ((unsigned)rr[7] << 16);
    wg.x = (unsigned)gg[0] | ((unsigned)gg[1] << 16);
    wg.y = (unsigned)gg[2] | ((unsigned)gg[3] << 16);
    wg.z = (unsigned)gg[4] | ((unsigned)gg[5] << 16);
    wg.w = (unsigned)gg[6] | ((unsigned)gg[7] << 16);
    wb.x = (unsigned)bb[0] | ((unsigned)bb[1] << 16);
    wb.y = (unsigned)bb[2] | ((unsigned)bb[3] << 16);
    wb.z = (unsigned)bb[4] | ((unsigned)bb[5] << 16);
    wb.w = (unsigned)bb[6] | ((unsigned)bb[7] << 16);
    dst[0] = wr; dst[1] = wg; dst[2] = wb;   // word 3 = pad, never read
}

// ---------------- trilinear apply: 1 entry line / pixel ----------------
__global__ __launch_bounds__(256) void apply_kernel(
    const float* __restrict__ img,
    const float* __restrict__ ws, float* __restrict__ dout)
{
    // XCD-batch swizzle: block i -> XCD i%8; batch = i&3 puts exactly one
    // batch's 2.3 MB LUT in each XCD's L2.
    const int b = blockIdx.x & 3;
    const int q = (blockIdx.x >> 2) * 256 + threadIdx.x;   // 0..518399
    const float4* base = (const float4*)(img + (size_t)b * 3 * NPIX);
    const float4 rv = base[q];
    const float4 gv = base[NPIX4 + q];
    const float4 bv = base[2 * NPIX4 + q];
    const uint4* lut = (const uint4*)((const char*)ws + WS_LUT64B) + (size_t)b * GGG * 4;

    float rrr[4] = {rv.x, rv.y, rv.z, rv.w};
    float ggg[4] = {gv.x, gv.y, gv.z, gv.w};
    float bbb[4] = {bv.x, bv.y, bv.z, bv.w};
    float o0[4], o1[4], o2[4];

    #pragma unroll
    for (int t = 0; t < 4; ++t) {
        const float xf = fminf(fmaxf(rrr[t] * 32.f, 0.f), 31.999998f);
        const float yf = fminf(fmaxf(ggg[t] * 32.f, 0.f), 31.999998f);
        const float zf = fminf(fmaxf(bbb[t] * 32.f, 0.f), 31.999998f);
        const int x0 = (int)xf, y0 = (int)yf, z0 = (int)zf;
        const float xd = xf - (float)x0, yd = yf - (float)y0, zd = zf - (float)z0;
        const int idx = (x0 * GN + y0) * GN + z0;
        const uint4* e = lut + (size_t)idx * 4;
        const uint4 er = e[0];
        const uint4 eg = e[1];
        const uint4 eb = e[2];
        // per channel: words = z-pairs for (x0y0),(x0y1),(x1y0),(x1y1)
        {
            const float z00 = bflo(er.x) + zd * (bfhi(er.x) - bflo(er.x));
            const float z01 = bflo(er.y) + zd * (bfhi(er.y) - bflo(er.y));
            const float z10 = bflo(er.z) + zd * (bfhi(er.z) - bflo(er.z));
            const float z11 = bflo(er.w) + zd * (bfhi(er.w) - bflo(er.w));
            const float y0v = z00 + yd * (z01 - z00);
            const float y1v = z10 + yd * (z11 - z10);
            o0[t] = y0v + xd * (y1v - y0v);
        }
        {
            const float z00 = bflo(eg.x) + zd * (bfhi(eg.x) - bflo(eg.x));
            const float z01 = bflo(eg.y) + zd * (bfhi(eg.y) - bflo(eg.y));
            const float z10 = bflo(eg.z) + zd * (bfhi(eg.z) - bflo(eg.z));
            const float z11 = bflo(eg.w) + zd * (bfhi(eg.w) - bflo(eg.w));
            const float y0v = z00 + yd * (z01 - z00);
            const float y1v = z10 + yd * (z11 - z10);
            o1[t] = y0v + xd * (y1v - y0v);
        }
        {
            const float z00 = bflo(eb.x) + zd * (bfhi(eb.x) - bflo(eb.x));
            const float z01 = bflo(eb.y) + zd * (bfhi(eb.y) - bflo(eb.y));
            const float z10 = bflo(eb.z) + zd * (bfhi(eb.z) - bflo(eb.z));
            const float z11 = bflo(eb.w) + zd * (bfhi(eb.w) - bflo(eb.w));
            const float y0v = z00 + yd * (z01 - z00);
            const float y1v = z10 + yd * (z11 - z10);
            o2[t] = y0v + xd * (y1v - y0v);
        }
    }
    float4* ob = (float4*)(dout + (size_t)b * 3 * NPIX);
    ob[q]             = make_float4(o0[0], o0[1], o0[2], o0[3]);
    ob[NPIX4 + q]     = make_float4(o1[0], o1[1], o1[2], o1[3]);
    ob[2 * NPIX4 + q] = make_float4(o2[0], o2[1], o2[2], o2[3]);
}

extern "C" void kernel_launch(void* const* d_in, const int* in_sizes, int n_in,
                              void* d_out, int out_size, void* d_ws, size_t ws_size,
                              hipStream_t stream)
{
    const float* img_lr   = (const float*)d_in[0];
    const float* img_full = (const float*)d_in[1];
    const float* bases    = (const float*)d_in[2];
    const float* wp_c1_w  = (const float*)d_in[3];
    const float* wp_c1_b  = (const float*)d_in[4];
    const float* wp_c2_w  = (const float*)d_in[5];
    const float* wp_c2_b  = (const float*)d_in[6];
    const float* wp_fc_w  = (const float*)d_in[7];
    const float* wp_fc_b  = (const float*)d_in[8];
    const float* rp_c1_w  = (const float*)d_in[9];
    const float* rp_c1_b  = (const float*)d_in[10];
    const float* rp_c2_w  = (const float*)d_in[11];
    const float* rp_c2_b  = (const float*)d_in[12];
    const float* fcu_w    = (const float*)d_in[13];
    const float* fcu_b    = (const float*)d_in[14];
    const float* fcv_w    = (const float*)d_in[15];
    const float* fcv_b    = (const float*)d_in[16];
    const float* fcw_w    = (const float*)d_in[17];
    const float* fcw_b    = (const float*)d_in[18];
    const float* fcc_w    = (const float*)d_in[19];
    const float* fcc_b    = (const float*)d_in[20];
    float* ws  = (float*)d_ws;
    float* out = (float*)d_out;

    // zero accumulated stats (conv2 means + |delta| sum)
    hipMemsetAsync(ws + WS_STATS, 0, 257 * sizeof(float), stream);

    conv1_kernel<<<dim3(64, 4, 2), 256, 0, stream>>>(
        img_lr, wp_c1_w, wp_c1_b, rp_c1_w, rp_c1_b, ws);
    conv2_kernel<<<dim3(16, 4, 2), 256, 0, stream>>>(
        wp_c2_w, wp_c2_b, rp_c2_w, rp_c2_b, ws);
    head_kernel<<<dim3(13), 256, 0, stream>>>(
        wp_fc_w, wp_fc_b, fcu_w, fcu_b, fcv_w, fcv_b, fcw_w, fcw_b, fcc_w, fcc_b,
        ws, out);
    lut_build_kernel<<<dim3((BATCH * GGG + 255) / 256), 256, 0, stream>>>(bases, ws, out);
    dnorm_kernel<<<1, 1, 0, stream>>>(ws, out);
    pack_kernel<<<dim3((BATCH * GGG + 255) / 256), 256, 0, stream>>>(out, ws);
    apply_kernel<<<dim3(BATCH * NPIX4 / 256), 256, 0, stream>>>(img_full, ws, out);
}

// Round 3
// 387.964 us; speedup vs baseline: 1.1881x; 1.1881x over previous
//
#include <hip/hip_runtime.h>
#include <stdint.h>

// ---------------- problem constants ----------------
#define GN   33
#define GG   1089      // 33*33
#define GGG  35937     // 33^3
#define BATCH 4
#define KK   8
#define RR   8
#define HFULL 1080
#define WFULL 1920
#define NPIX (HFULL*WFULL)          // 2,073,600 per channel
#define NPIX4 (NPIX/4)              // 518,400 float4 per channel

// d_out layout (floats): out | alpha | delta | L | delta_norm
#define OUT_ALPHA 24883200
#define OUT_DELTA 24883232
#define OUT_L     25314476
#define OUT_DNORM 25745720

// ---------------- workspace layout ----------------
// bytes [0, 9,199,872): 64B-entry packed LUT (4*35937 entries)
// floats from WS_PART: encoder partial sums [enc2][b4][tile32][o32] = 8192
// floats from WS_DN:   564 per-block |delta| partials
#define WS_LUT64B 0
#define WS_PART   2300000
#define WS_DN     2308192
#define NBLK_PER_B 141     // lut blocks per batch (141*256 >= 35937)

__device__ __forceinline__ unsigned short f2bf(float f) {
    unsigned u = __float_as_uint(f);
    unsigned r = (u + 0x7fffu + ((u >> 16) & 1u)) >> 16;
    return (unsigned short)r;
}
__device__ __forceinline__ float bflo(unsigned u) { return __uint_as_float(u << 16); }
__device__ __forceinline__ float bfhi(unsigned u) { return __uint_as_float(u & 0xffff0000u); }

// ---------------- fused encoder: conv1(3->16,s2) + conv2(16->32,s2) + mean partials ----------------
// block = (enc, b, rt 0..15, ct 0..1); out tile = conv2 rows 4rt..4rt+3, cols 32ct..32ct+31
__global__ __launch_bounds__(256) void encoder_kernel(
    const float* __restrict__ img,
    const float* __restrict__ w1wp, const float* __restrict__ b1wp,
    const float* __restrict__ w2wp, const float* __restrict__ b2wp,
    const float* __restrict__ w1rp, const float* __restrict__ b1rp,
    const float* __restrict__ w2rp, const float* __restrict__ b2rp,
    float* __restrict__ ws)
{
    const int bi = blockIdx.x;
    const int enc = bi >> 7, b = (bi >> 5) & 3, rt = (bi >> 1) & 15, ct = bi & 1;
    const float* w1 = enc ? w1rp : w1wp;
    const float* b1 = enc ? b1rp : b1wp;
    const float* w2 = enc ? w2rp : w2wp;
    const float* b2 = enc ? b2rp : b2wp;
    __shared__ float simg[3][19][132];   // img rows 16rt-3..16rt+15, cols 128ct-3..128ct+127
    __shared__ float sh1[4][9][66];      // h1 chunk: rows 8rt-1..8rt+7, cols 64ct-1..64ct+63
    __shared__ float red[4][16];
    const float* imb = img + (size_t)b * 3 * 65536;
    const int tid = threadIdx.x;

    for (int l = tid; l < 3 * 19 * 131; l += 256) {
        const int c = l / (19 * 131);
        const int rem = l - c * (19 * 131);
        const int rw = rem / 131, cl = rem - rw * 131;
        const int gr = 16 * rt - 3 + rw, gc = 128 * ct - 3 + cl;
        float v = 0.f;
        if ((unsigned)gr < 256u && (unsigned)gc < 256u)
            v = imb[(c << 16) + (gr << 8) + gc];
        simg[c][rw][cl] = v;
    }
    __syncthreads();

    const int p = tid & 127, h = tid >> 7;       // position, channel-half
    const int prow = p >> 5, pcol = p & 31;
    float acc[16];
    #pragma unroll
    for (int o = 0; o < 16; ++o) acc[o] = b2[h * 16 + o];

    for (int cc0 = 0; cc0 < 16; cc0 += 4) {
        if (cc0) __syncthreads();                // sh1 reuse guard
        // conv1 for channels cc0..cc0+3 over the 9x65 h1 region
        for (int l = tid; l < 4 * 9 * 65; l += 256) {
            const int oc = l / (9 * 65);
            const int rem = l - oc * (9 * 65);
            const int r = rem / 65, cl = rem - r * 65;
            const int hrow = 8 * rt - 1 + r, hcol = 64 * ct - 1 + cl;
            float v = 0.f;
            if ((unsigned)hrow < 128u && (unsigned)hcol < 128u) {
                float a1 = b1[cc0 + oc];
                const float* wo = w1 + (cc0 + oc) * 27;
                #pragma unroll
                for (int c = 0; c < 3; ++c)
                    #pragma unroll
                    for (int ky = 0; ky < 3; ++ky)
                        #pragma unroll
                        for (int kx = 0; kx < 3; ++kx)
                            a1 += wo[c * 9 + ky * 3 + kx] * simg[c][2 * r + ky][2 * cl + kx];
                v = fmaxf(a1, 0.f);
            }
            sh1[oc][r][cl] = v;
        }
        __syncthreads();
        // conv2 partial accumulate
        #pragma unroll
        for (int cc = 0; cc < 4; ++cc) {
            float vv[9];
            #pragma unroll
            for (int ky = 0; ky < 3; ++ky)
                #pragma unroll
                for (int kx = 0; kx < 3; ++kx)
                    vv[ky * 3 + kx] = sh1[cc][2 * prow + ky][2 * pcol + kx];
            #pragma unroll
            for (int o = 0; o < 16; ++o) {
                const float* wo = w2 + (h * 16 + o) * 144 + (cc0 + cc) * 9;
                #pragma unroll
                for (int k = 0; k < 9; ++k) acc[o] += wo[k] * vv[k];
            }
        }
    }
    // relu then reduce over this block's 128 positions per channel
    const int lane = tid & 63, wv = tid >> 6;
    #pragma unroll
    for (int o = 0; o < 16; ++o) {
        float v = fmaxf(acc[o], 0.f);
        #pragma unroll
        for (int off = 32; off; off >>= 1) v += __shfl_down(v, off);
        if (lane == 0) red[wv][o] = v;
    }
    __syncthreads();
    if (tid < 32) {
        const int o = tid & 15, g = tid >> 4;    // g=0: waves 0+1 (ch o), g=1: waves 2+3 (ch 16+o)
        const float s = red[g * 2][o] + red[g * 2 + 1][o];
        ws[WS_PART + ((enc * 4 + b) * 32 + (rt * 2 + ct)) * 32 + g * 16 + o] = s;
    }
}

// ---------------- fused heads + LUT build + pack ----------------
__global__ __launch_bounds__(256) void lut_kernel(
    const float* __restrict__ bases,
    const float* __restrict__ wp_fc_w, const float* __restrict__ wp_fc_b,
    const float* __restrict__ fcu_w, const float* __restrict__ fcu_b,
    const float* __restrict__ fcv_w, const float* __restrict__ fcv_b,
    const float* __restrict__ fcw_w, const float* __restrict__ fcw_b,
    const float* __restrict__ fcc_w, const float* __restrict__ fcc_b,
    float* __restrict__ ws, float* __restrict__ dout)
{
    const int b = blockIdx.x / NBLK_PER_B;
    const int blk = blockIdx.x - b * NBLK_PER_B;
    const int tid = threadIdx.x;
    __shared__ float mean[2][32];
    __shared__ float U[264], V[264], W[264], Cc[24], Al[8];

    // phase 1a: reduce encoder partials for this batch
    if (tid < 64) {
        const int enc = tid >> 5, o = tid & 31;
        const float* pp = ws + WS_PART + (enc * 4 + b) * 1024 + o;
        float s = 0.f;
        #pragma unroll
        for (int i = 0; i < 32; ++i) s += pp[i * 32];
        mean[enc][o] = s * (1.f / 4096.f);
    }
    __syncthreads();
    // phase 1b: FC heads (redundant per block; ~26k MAC)
    for (int r = tid; r < 824; r += 256) {
        if (r < 8) {
            const float* row = wp_fc_w + r * 32;
            float a = wp_fc_b[r];
            #pragma unroll 8
            for (int q = 0; q < 32; ++q) a += row[q] * mean[0][q];
            Al[r] = a;
            dout[OUT_ALPHA + b * 8 + r] = a;   // redundant identical writes across blocks: benign
        } else if (r < 272) {
            const int jj = r - 8;
            const float* row = fcu_w + jj * 32;
            float a = fcu_b[jj];
            #pragma unroll 8
            for (int q = 0; q < 32; ++q) a += row[q] * mean[1][q];
            U[jj] = a;
        } else if (r < 536) {
            const int jj = r - 272;
            const float* row = fcv_w + jj * 32;
            float a = fcv_b[jj];
            #pragma unroll 8
            for (int q = 0; q < 32; ++q) a += row[q] * mean[1][q];
            V[jj] = a;
        } else if (r < 800) {
            const int jj = r - 536;
            const float* row = fcw_w + jj * 32;
            float a = fcw_b[jj];
            #pragma unroll 8
            for (int q = 0; q < 32; ++q) a += row[q] * mean[1][q];
            W[jj] = a;
        } else {
            const int jj = r - 800;
            const float* row = fcc_w + jj * 32;
            float a = fcc_b[jj];
            #pragma unroll 8
            for (int q = 0; q < 32; ++q) a += row[q] * mean[1][q];
            Cc[jj] = a;
        }
    }
    __syncthreads();

    // phase 2: per-site delta/L + 8-corner recompute + pack
    const int s = blk * 256 + tid;
    float sum3 = 0.f;
    if (s < GGG) {
        const int x = s / GG;
        const int rem = s - x * GG;
        const int y = rem / GN, z = rem - y * GN;
        const int x1 = min(x + 1, GN - 1), y1 = min(y + 1, GN - 1), z1 = min(z + 1, GN - 1);
        float ux[2][8], vy[2][8], wz[2][8];
        #pragma unroll
        for (int r = 0; r < 8; ++r) {
            ux[0][r] = U[r * GN + x];  ux[1][r] = U[r * GN + x1];
            vy[0][r] = V[r * GN + y];  vy[1][r] = V[r * GN + y1];
            wz[0][r] = W[r * GN + z];  wz[1][r] = W[r * GN + z1];
        }
        float d0 = 0.f, d1 = 0.f, d2 = 0.f;
        float cl[8][3];
        #pragma unroll
        for (int k8 = 0; k8 < 8; ++k8) {
            const int bx = (k8 >> 2) & 1, by = (k8 >> 1) & 1, bz = k8 & 1;
            const int xi = bx ? x1 : x, yi = by ? y1 : y, zi = bz ? z1 : z;
            const int sc = (xi * GN + yi) * GN + zi;
            float l0 = 0.f, l1 = 0.f, l2 = 0.f;
            #pragma unroll
            for (int r = 0; r < 8; ++r) {
                const float t = ux[bx][r] * vy[by][r] * wz[bz][r];
                l0 += t * Cc[r * 3 + 0];
                l1 += t * Cc[r * 3 + 1];
                l2 += t * Cc[r * 3 + 2];
            }
            if (k8 == 0) { d0 = l0; d1 = l1; d2 = l2; }
            const float* bp = bases + (size_t)sc * 3;
            #pragma unroll
            for (int k = 0; k < 8; ++k) {
                const float a = Al[k];
                l0 += a * bp[(size_t)k * GGG * 3 + 0];
                l1 += a * bp[(size_t)k * GGG * 3 + 1];
                l2 += a * bp[(size_t)k * GGG * 3 + 2];
            }
            cl[k8][0] = l0; cl[k8][1] = l1; cl[k8][2] = l2;
        }
        const size_t o3 = ((size_t)b * GGG + s) * 3;
        dout[OUT_DELTA + o3 + 0] = d0;
        dout[OUT_DELTA + o3 + 1] = d1;
        dout[OUT_DELTA + o3 + 2] = d2;
        dout[OUT_L + o3 + 0] = cl[0][0];
        dout[OUT_L + o3 + 1] = cl[0][1];
        dout[OUT_L + o3 + 2] = cl[0][2];
        // pack: word = z-pair (lo=z0, hi=z1) per (x,y) corner, per channel
        uint4* dst = (uint4*)((char*)ws + WS_LUT64B) + ((size_t)b * GGG + s) * 4;
        uint4 wr, wg, wb;
        wr.x = (unsigned)f2bf(cl[0][0]) | ((unsigned)f2bf(cl[1][0]) << 16);
        wr.y = (unsigned)f2bf(cl[2][0]) | ((unsigned)f2bf(cl[3][0]) << 16);
        wr.z = (unsigned)f2bf(cl[4][0]) | ((unsigned)f2bf(cl[5][0]) << 16);
        wr.w = (unsigned)f2bf(cl[6][0]) | ((unsigned)f2bf(cl[7][0]) << 16);
        wg.x = (unsigned)f2bf(cl[0][1]) | ((unsigned)f2bf(cl[1][1]) << 16);
        wg.y = (unsigned)f2bf(cl[2][1]) | ((unsigned)f2bf(cl[3][1]) << 16);
        wg.z = (unsigned)f2bf(cl[4][1]) | ((unsigned)f2bf(cl[5][1]) << 16);
        wg.w = (unsigned)f2bf(cl[6][1]) | ((unsigned)f2bf(cl[7][1]) << 16);
        wb.x = (unsigned)f2bf(cl[0][2]) | ((unsigned)f2bf(cl[1][2]) << 16);
        wb.y = (unsigned)f2bf(cl[2][2]) | ((unsigned)f2bf(cl[3][2]) << 16);
        wb.z = (unsigned)f2bf(cl[4][2]) | ((unsigned)f2bf(cl[5][2]) << 16);
        wb.w = (unsigned)f2bf(cl[6][2]) | ((unsigned)f2bf(cl[7][2]) << 16);
        dst[0] = wr; dst[1] = wg; dst[2] = wb;
        sum3 = fabsf(d0) + fabsf(d1) + fabsf(d2);
    }
    // per-block |delta| partial
    #pragma unroll
    for (int off = 32; off; off >>= 1) sum3 += __shfl_down(sum3, off);
    __shared__ float s4[4];
    const int lane = tid & 63, wid = tid >> 6;
    if (!lane) s4[wid] = sum3;
    __syncthreads();
    if (!tid) ws[WS_DN + blockIdx.x] = s4[0] + s4[1] + s4[2] + s4[3];
}

// ---------------- trilinear apply (+ dnorm finish in block 0) ----------------
__global__ __launch_bounds__(256) void apply_kernel(
    const float* __restrict__ img,
    const float* __restrict__ ws, float* __restrict__ dout)
{
    if (blockIdx.x == 0 && threadIdx.x < 64) {
        float s = 0.f;
        for (int i = threadIdx.x; i < BATCH * NBLK_PER_B; i += 64) s += ws[WS_DN + i];
        #pragma unroll
        for (int off = 32; off; off >>= 1) s += __shfl_down(s, off);
        if (threadIdx.x == 0)
            dout[OUT_DNORM] = s * (1.0f / (float)(BATCH * GGG * 3));
    }
    // XCD-batch swizzle: round-robin block->XCD; batch = i&3 keeps one batch's
    // 2.3 MB LUT per XCD L2.
    const int b = blockIdx.x & 3;
    const int q = (blockIdx.x >> 2) * 256 + threadIdx.x;
    const float4* base = (const float4*)(img + (size_t)b * 3 * NPIX);
    const float4 rv = base[q];
    const float4 gv = base[NPIX4 + q];
    const float4 bv = base[2 * NPIX4 + q];
    const uint4* lut = (const uint4*)((const char*)ws + WS_LUT64B) + (size_t)b * GGG * 4;

    float rrr[4] = {rv.x, rv.y, rv.z, rv.w};
    float ggg[4] = {gv.x, gv.y, gv.z, gv.w};
    float bbb[4] = {bv.x, bv.y, bv.z, bv.w};
    int idx[4]; float xd[4], yd[4], zd[4];
    #pragma unroll
    for (int t = 0; t < 4; ++t) {
        const float xf = fminf(fmaxf(rrr[t] * 32.f, 0.f), 31.999998f);
        const float yf = fminf(fmaxf(ggg[t] * 32.f, 0.f), 31.999998f);
        const float zf = fminf(fmaxf(bbb[t] * 32.f, 0.f), 31.999998f);
        const int x0 = (int)xf, y0 = (int)yf, z0 = (int)zf;
        xd[t] = xf - (float)x0; yd[t] = yf - (float)y0; zd[t] = zf - (float)z0;
        idx[t] = (x0 * GN + y0) * GN + z0;
    }
    // batch all 12 gathers before any blend compute
    uint4 er[4], eg[4], eb[4];
    #pragma unroll
    for (int t = 0; t < 4; ++t) {
        const uint4* e = lut + (size_t)idx[t] * 4;
        er[t] = e[0]; eg[t] = e[1]; eb[t] = e[2];
    }
    float o0[4], o1[4], o2[4];
    #pragma unroll
    for (int t = 0; t < 4; ++t) {
        {
            const float z00 = bflo(er[t].x) + zd[t] * (bfhi(er[t].x) - bflo(er[t].x));
            const float z01 = bflo(er[t].y) + zd[t] * (bfhi(er[t].y) - bflo(er[t].y));
            const float z10 = bflo(er[t].z) + zd[t] * (bfhi(er[t].z) - bflo(er[t].z));
            const float z11 = bflo(er[t].w) + zd[t] * (bfhi(er[t].w) - bflo(er[t].w));
            const float y0v = z00 + yd[t] * (z01 - z00);
            const float y1v = z10 + yd[t] * (z11 - z10);
            o0[t] = y0v + xd[t] * (y1v - y0v);
        }
        {
            const float z00 = bflo(eg[t].x) + zd[t] * (bfhi(eg[t].x) - bflo(eg[t].x));
            const float z01 = bflo(eg[t].y) + zd[t] * (bfhi(eg[t].y) - bflo(eg[t].y));
            const float z10 = bflo(eg[t].z) + zd[t] * (bfhi(eg[t].z) - bflo(eg[t].z));
            const float z11 = bflo(eg[t].w) + zd[t] * (bfhi(eg[t].w) - bflo(eg[t].w));
            const float y0v = z00 + yd[t] * (z01 - z00);
            const float y1v = z10 + yd[t] * (z11 - z10);
            o1[t] = y0v + xd[t] * (y1v - y0v);
        }
        {
            const float z00 = bflo(eb[t].x) + zd[t] * (bfhi(eb[t].x) - bflo(eb[t].x));
            const float z01 = bflo(eb[t].y) + zd[t] * (bfhi(eb[t].y) - bflo(eb[t].y));
            const float z10 = bflo(eb[t].z) + zd[t] * (bfhi(eb[t].z) - bflo(eb[t].z));
            const float z11 = bflo(eb[t].w) + zd[t] * (bfhi(eb[t].w) - bflo(eb[t].w));
            const float y0v = z00 + yd[t] * (z01 - z00);
            const float y1v = z10 + yd[t] * (z11 - z10);
            o2[t] = y0v + xd[t] * (y1v - y0v);
        }
    }
    float4* ob = (float4*)(dout + (size_t)b * 3 * NPIX);
    ob[q]             = make_float4(o0[0], o0[1], o0[2], o0[3]);
    ob[NPIX4 + q]     = make_float4(o1[0], o1[1], o1[2], o1[3]);
    ob[2 * NPIX4 + q] = make_float4(o2[0], o2[1], o2[2], o2[3]);
}

extern "C" void kernel_launch(void* const* d_in, const int* in_sizes, int n_in,
                              void* d_out, int out_size, void* d_ws, size_t ws_size,
                              hipStream_t stream)
{
    const float* img_lr   = (const float*)d_in[0];
    const float* img_full = (const float*)d_in[1];
    const float* bases    = (const float*)d_in[2];
    const float* wp_c1_w  = (const float*)d_in[3];
    const float* wp_c1_b  = (const float*)d_in[4];
    const float* wp_c2_w  = (const float*)d_in[5];
    const float* wp_c2_b  = (const float*)d_in[6];
    const float* wp_fc_w  = (const float*)d_in[7];
    const float* wp_fc_b  = (const float*)d_in[8];
    const float* rp_c1_w  = (const float*)d_in[9];
    const float* rp_c1_b  = (const float*)d_in[10];
    const float* rp_c2_w  = (const float*)d_in[11];
    const float* rp_c2_b  = (const float*)d_in[12];
    const float* fcu_w    = (const float*)d_in[13];
    const float* fcu_b    = (const float*)d_in[14];
    const float* fcv_w    = (const float*)d_in[15];
    const float* fcv_b    = (const float*)d_in[16];
    const float* fcw_w    = (const float*)d_in[17];
    const float* fcw_b    = (const float*)d_in[18];
    const float* fcc_w    = (const float*)d_in[19];
    const float* fcc_b    = (const float*)d_in[20];
    float* ws  = (float*)d_ws;
    float* out = (float*)d_out;

    encoder_kernel<<<dim3(256), 256, 0, stream>>>(
        img_lr, wp_c1_w, wp_c1_b, wp_c2_w, wp_c2_b,
        rp_c1_w, rp_c1_b, rp_c2_w, rp_c2_b, ws);
    lut_kernel<<<dim3(BATCH * NBLK_PER_B), 256, 0, stream>>>(
        bases, wp_fc_w, wp_fc_b, fcu_w, fcu_b, fcv_w, fcv_b,
        fcw_w, fcw_b, fcc_w, fcc_b, ws, out);
    apply_kernel<<<dim3(BATCH * NPIX4 / 256), 256, 0, stream>>>(img_full, ws, out);
}

// Round 5
// 365.853 us; speedup vs baseline: 1.2599x; 1.0604x over previous
//
#include <hip/hip_runtime.h>
#include <stdint.h>

// ---------------- problem constants ----------------
#define GN   33
#define GG   1089      // 33*33
#define GGG  35937     // 33^3
#define BATCH 4
#define HFULL 1080
#define WFULL 1920
#define NPIX (HFULL*WFULL)          // 2,073,600 per channel
#define NPIX4 (NPIX/4)              // 518,400 float4 per channel

// d_out layout (floats): out | alpha | delta | L | delta_norm
#define OUT_ALPHA 24883200
#define OUT_DELTA 24883232
#define OUT_L     25314476
#define OUT_DNORM 25745720

// ---------------- workspace layout ----------------
// bytes [0, 9,199,872): 64B-entry packed LUT (4*35937 entries)
#define WS_LUT64B 0
#define WS_PART   2300000   // encoder partials [enc2][b4][tile32][o32]
#define WS_DN     2308192   // 132 per-block |delta| partials
#define NLUTBLK   132       // 4 batches * 33 x-planes

// native clang vectors (required by __builtin_nontemporal_*)
typedef float  float4n __attribute__((ext_vector_type(4)));
typedef unsigned int uint4n __attribute__((ext_vector_type(4)));

__device__ __forceinline__ unsigned short f2bf(float f) {
    unsigned u = __float_as_uint(f);
    unsigned r = (u + 0x7fffu + ((u >> 16) & 1u)) >> 16;
    return (unsigned short)r;
}
__device__ __forceinline__ float bflo(unsigned u) { return __uint_as_float(u << 16); }
__device__ __forceinline__ float bfhi(unsigned u) { return __uint_as_float(u & 0xffff0000u); }

// ---------------- fused encoder: conv1(3->16,s2) + conv2(16->32,s2) + mean partials ----------------
__global__ __launch_bounds__(256) void encoder_kernel(
    const float* __restrict__ img,
    const float* __restrict__ w1wp, const float* __restrict__ b1wp,
    const float* __restrict__ w2wp, const float* __restrict__ b2wp,
    const float* __restrict__ w1rp, const float* __restrict__ b1rp,
    const float* __restrict__ w2rp, const float* __restrict__ b2rp,
    float* __restrict__ ws)
{
    const int bi = blockIdx.x;
    const int enc = bi >> 7, b = (bi >> 5) & 3, rt = (bi >> 1) & 15, ct = bi & 1;
    const float* w1 = enc ? w1rp : w1wp;
    const float* b1 = enc ? b1rp : b1wp;
    const float* w2 = enc ? w2rp : w2wp;
    const float* b2 = enc ? b2rp : b2wp;
    __shared__ float simg[3][19][132];
    __shared__ float sh1[4][9][66];
    __shared__ float red[4][16];
    const float* imb = img + (size_t)b * 3 * 65536;
    const int tid = threadIdx.x;

    for (int l = tid; l < 3 * 19 * 131; l += 256) {
        const int c = l / (19 * 131);
        const int rem = l - c * (19 * 131);
        const int rw = rem / 131, cl = rem - rw * 131;
        const int gr = 16 * rt - 3 + rw, gc = 128 * ct - 3 + cl;
        float v = 0.f;
        if ((unsigned)gr < 256u && (unsigned)gc < 256u)
            v = imb[(c << 16) + (gr << 8) + gc];
        simg[c][rw][cl] = v;
    }
    __syncthreads();

    const int p = tid & 127, h = tid >> 7;
    const int prow = p >> 5, pcol = p & 31;
    float acc[16];
    #pragma unroll
    for (int o = 0; o < 16; ++o) acc[o] = b2[h * 16 + o];

    for (int cc0 = 0; cc0 < 16; cc0 += 4) {
        if (cc0) __syncthreads();
        for (int l = tid; l < 4 * 9 * 65; l += 256) {
            const int oc = l / (9 * 65);
            const int rem = l - oc * (9 * 65);
            const int r = rem / 65, cl = rem - r * 65;
            const int hrow = 8 * rt - 1 + r, hcol = 64 * ct - 1 + cl;
            float v = 0.f;
            if ((unsigned)hrow < 128u && (unsigned)hcol < 128u) {
                float a1 = b1[cc0 + oc];
                const float* wo = w1 + (cc0 + oc) * 27;
                #pragma unroll
                for (int c = 0; c < 3; ++c)
                    #pragma unroll
                    for (int ky = 0; ky < 3; ++ky)
                        #pragma unroll
                        for (int kx = 0; kx < 3; ++kx)
                            a1 += wo[c * 9 + ky * 3 + kx] * simg[c][2 * r + ky][2 * cl + kx];
                v = fmaxf(a1, 0.f);
            }
            sh1[oc][r][cl] = v;
        }
        __syncthreads();
        #pragma unroll
        for (int cc = 0; cc < 4; ++cc) {
            float vv[9];
            #pragma unroll
            for (int ky = 0; ky < 3; ++ky)
                #pragma unroll
                for (int kx = 0; kx < 3; ++kx)
                    vv[ky * 3 + kx] = sh1[cc][2 * prow + ky][2 * pcol + kx];
            #pragma unroll
            for (int o = 0; o < 16; ++o) {
                const float* wo = w2 + (h * 16 + o) * 144 + (cc0 + cc) * 9;
                #pragma unroll
                for (int k = 0; k < 9; ++k) acc[o] += wo[k] * vv[k];
            }
        }
    }
    const int lane = tid & 63, wv = tid >> 6;
    #pragma unroll
    for (int o = 0; o < 16; ++o) {
        float v = fmaxf(acc[o], 0.f);
        #pragma unroll
        for (int off = 32; off; off >>= 1) v += __shfl_down(v, off);
        if (lane == 0) red[wv][o] = v;
    }
    __syncthreads();
    if (tid < 32) {
        const int o = tid & 15, g = tid >> 4;
        const float s = red[g * 2][o] + red[g * 2 + 1][o];
        ws[WS_PART + ((enc * 4 + b) * 32 + (rt * 2 + ct)) * 32 + g * 16 + o] = s;
    }
}

// ---------------- fused heads + plane-pair LUT build + pack ----------------
// block = (b, x-plane). Computes planes x and x+1 ONCE each into LDS
// (2x total redundancy vs 8x per-corner recompute), then packs plane x.
__global__ __launch_bounds__(256) void lut_kernel(
    const float* __restrict__ bases,
    const float* __restrict__ wp_fc_w, const float* __restrict__ wp_fc_b,
    const float* __restrict__ fcu_w, const float* __restrict__ fcu_b,
    const float* __restrict__ fcv_w, const float* __restrict__ fcv_b,
    const float* __restrict__ fcw_w, const float* __restrict__ fcw_b,
    const float* __restrict__ fcc_w, const float* __restrict__ fcc_b,
    float* __restrict__ ws, float* __restrict__ dout)
{
    const int b = blockIdx.x & 3;
    const int x = blockIdx.x >> 2;          // 0..32
    const int x1 = min(x + 1, GN - 1);
    const int tid = threadIdx.x;
    __shared__ float mean[2][32];
    __shared__ float U[264], V[264], W[264], Cc[24], Al[8];
    __shared__ float Lp[2][GG * 3];         // 26.1 KB: L for planes x, x1

    // phase 1a: reduce encoder partials
    if (tid < 64) {
        const int enc = tid >> 5, o = tid & 31;
        const float* pp = ws + WS_PART + (enc * 4 + b) * 1024 + o;
        float s = 0.f;
        #pragma unroll
        for (int i = 0; i < 32; ++i) s += pp[i * 32];
        mean[enc][o] = s * (1.f / 4096.f);
    }
    __syncthreads();
    // phase 1b: FC heads (redundant per block, trivial)
    for (int r = tid; r < 824; r += 256) {
        if (r < 8) {
            const float* row = wp_fc_w + r * 32;
            float a = wp_fc_b[r];
            #pragma unroll 8
            for (int q = 0; q < 32; ++q) a += row[q] * mean[0][q];
            Al[r] = a;
            dout[OUT_ALPHA + b * 8 + r] = a;
        } else if (r < 272) {
            const int jj = r - 8;
            const float* row = fcu_w + jj * 32;
            float a = fcu_b[jj];
            #pragma unroll 8
            for (int q = 0; q < 32; ++q) a += row[q] * mean[1][q];
            U[jj] = a;
        } else if (r < 536) {
            const int jj = r - 272;
            const float* row = fcv_w + jj * 32;
            float a = fcv_b[jj];
            #pragma unroll 8
            for (int q = 0; q < 32; ++q) a += row[q] * mean[1][q];
            V[jj] = a;
        } else if (r < 800) {
            const int jj = r - 536;
            const float* row = fcw_w + jj * 32;
            float a = fcw_b[jj];
            #pragma unroll 8
            for (int q = 0; q < 32; ++q) a += row[q] * mean[1][q];
            W[jj] = a;
        } else {
            const int jj = r - 800;
            const float* row = fcc_w + jj * 32;
            float a = fcc_b[jj];
            #pragma unroll 8
            for (int q = 0; q < 32; ++q) a += row[q] * mean[1][q];
            Cc[jj] = a;
        }
    }
    __syncthreads();

    float ux0[8], ux1[8], cr[8][3];
    #pragma unroll
    for (int r = 0; r < 8; ++r) {
        ux0[r] = U[r * GN + x];
        ux1[r] = U[r * GN + x1];
        cr[r][0] = Cc[r * 3 + 0];
        cr[r][1] = Cc[r * 3 + 1];
        cr[r][2] = Cc[r * 3 + 2];
    }

    // phase 2: compute L for both planes, coalesced bases reads
    float sum3 = 0.f;
    #pragma unroll
    for (int px = 0; px < 2; ++px) {
        const int xi = px ? x1 : x;
        for (int i = tid; i < GG; i += 256) {
            const int y = i / GN, z = i - y * GN;
            float d0 = 0.f, d1 = 0.f, d2 = 0.f;
            #pragma unroll
            for (int r = 0; r < 8; ++r) {
                const float t = (px ? ux1[r] : ux0[r]) * V[r * GN + y] * W[r * GN + z];
                d0 += t * cr[r][0];
                d1 += t * cr[r][1];
                d2 += t * cr[r][2];
            }
            float l0 = d0, l1 = d1, l2 = d2;
            const float* bp = bases + (size_t)(xi * GG + i) * 3;
            #pragma unroll
            for (int k = 0; k < 8; ++k) {
                const float a = Al[k];
                const float* bk = bp + (size_t)k * GGG * 3;
                l0 += a * bk[0];
                l1 += a * bk[1];
                l2 += a * bk[2];
            }
            Lp[px][i * 3 + 0] = l0;
            Lp[px][i * 3 + 1] = l1;
            Lp[px][i * 3 + 2] = l2;
            if (px == 0) {
                const size_t o3 = ((size_t)b * GGG + x * GG + i) * 3;
                dout[OUT_DELTA + o3 + 0] = d0;
                dout[OUT_DELTA + o3 + 1] = d1;
                dout[OUT_DELTA + o3 + 2] = d2;
                dout[OUT_L + o3 + 0] = l0;
                dout[OUT_L + o3 + 1] = l1;
                dout[OUT_L + o3 + 2] = l2;
                sum3 += fabsf(d0) + fabsf(d1) + fabsf(d2);
            }
        }
    }
    __syncthreads();

    // phase 3: pack entries for plane x from LDS
    for (int i = tid; i < GG; i += 256) {
        const int y = i / GN, z = i - y * GN;
        const int y1 = min(y + 1, GN - 1), z1 = min(z + 1, GN - 1);
        const int i00 = (y  * GN + z ) * 3, i01 = (y  * GN + z1) * 3;
        const int i10 = (y1 * GN + z ) * 3, i11 = (y1 * GN + z1) * 3;
        uint4 wr, wg, wb;
        #pragma unroll
        for (int c = 0; c < 3; ++c) {
            const unsigned w00 = (unsigned)f2bf(Lp[0][i00 + c]) | ((unsigned)f2bf(Lp[0][i01 + c]) << 16);
            const unsigned w01 = (unsigned)f2bf(Lp[0][i10 + c]) | ((unsigned)f2bf(Lp[0][i11 + c]) << 16);
            const unsigned w10 = (unsigned)f2bf(Lp[1][i00 + c]) | ((unsigned)f2bf(Lp[1][i01 + c]) << 16);
            const unsigned w11 = (unsigned)f2bf(Lp[1][i10 + c]) | ((unsigned)f2bf(Lp[1][i11 + c]) << 16);
            uint4& wv = c == 0 ? wr : (c == 1 ? wg : wb);
            wv.x = w00; wv.y = w01; wv.z = w10; wv.w = w11;
        }
        uint4* dst = (uint4*)((char*)ws + WS_LUT64B) + ((size_t)b * GGG + x * GG + i) * 4;
        dst[0] = wr; dst[1] = wg; dst[2] = wb;
    }

    // per-block |delta| partial
    #pragma unroll
    for (int off = 32; off; off >>= 1) sum3 += __shfl_down(sum3, off);
    __shared__ float s4[4];
    const int lane = tid & 63, wid = tid >> 6;
    if (!lane) s4[wid] = sum3;
    __syncthreads();
    if (!tid) ws[WS_DN + blockIdx.x] = s4[0] + s4[1] + s4[2] + s4[3];
}

// ---------------- trilinear apply (+ dnorm finish in block 0) ----------------
// NT loads/stores on the img/out streams keep the 2.3 MB/XCD LUT resident in L2.
__global__ __launch_bounds__(256) void apply_kernel(
    const float* __restrict__ img,
    const float* __restrict__ ws, float* __restrict__ dout)
{
    if (blockIdx.x == 0 && threadIdx.x < 64) {
        float s = 0.f;
        for (int i = threadIdx.x; i < NLUTBLK; i += 64) s += ws[WS_DN + i];
        #pragma unroll
        for (int off = 32; off; off >>= 1) s += __shfl_down(s, off);
        if (threadIdx.x == 0)
            dout[OUT_DNORM] = s * (1.0f / (float)(BATCH * GGG * 3));
    }
    const int b = blockIdx.x & 3;     // with round-robin block->XCD, XCD j sees only batch j&3
    const int q = (blockIdx.x >> 2) * 256 + threadIdx.x;
    const float4n* base = (const float4n*)(img + (size_t)b * 3 * NPIX);
    const float4n rv = __builtin_nontemporal_load(&base[q]);
    const float4n gv = __builtin_nontemporal_load(&base[NPIX4 + q]);
    const float4n bv = __builtin_nontemporal_load(&base[2 * NPIX4 + q]);
    const uint4* lut = (const uint4*)((const char*)ws + WS_LUT64B) + (size_t)b * GGG * 4;

    float rrr[4] = {rv.x, rv.y, rv.z, rv.w};
    float ggg[4] = {gv.x, gv.y, gv.z, gv.w};
    float bbb[4] = {bv.x, bv.y, bv.z, bv.w};
    int idx[4]; float xd[4], yd[4], zd[4];
    #pragma unroll
    for (int t = 0; t < 4; ++t) {
        const float xf = fminf(fmaxf(rrr[t] * 32.f, 0.f), 31.999998f);
        const float yf = fminf(fmaxf(ggg[t] * 32.f, 0.f), 31.999998f);
        const float zf = fminf(fmaxf(bbb[t] * 32.f, 0.f), 31.999998f);
        const int x0 = (int)xf, y0 = (int)yf, z0 = (int)zf;
        xd[t] = xf - (float)x0; yd[t] = yf - (float)y0; zd[t] = zf - (float)z0;
        idx[t] = (x0 * GN + y0) * GN + z0;
    }
    uint4 er[4], eg[4], eb[4];
    #pragma unroll
    for (int t = 0; t < 4; ++t) {
        const uint4* e = lut + (size_t)idx[t] * 4;
        er[t] = e[0]; eg[t] = e[1]; eb[t] = e[2];
    }
    float o0[4], o1[4], o2[4];
    #pragma unroll
    for (int t = 0; t < 4; ++t) {
        {
            const float z00 = bflo(er[t].x) + zd[t] * (bfhi(er[t].x) - bflo(er[t].x));
            const float z01 = bflo(er[t].y) + zd[t] * (bfhi(er[t].y) - bflo(er[t].y));
            const float z10 = bflo(er[t].z) + zd[t] * (bfhi(er[t].z) - bflo(er[t].z));
            const float z11 = bflo(er[t].w) + zd[t] * (bfhi(er[t].w) - bflo(er[t].w));
            const float y0v = z00 + yd[t] * (z01 - z00);
            const float y1v = z10 + yd[t] * (z11 - z10);
            o0[t] = y0v + xd[t] * (y1v - y0v);
        }
        {
            const float z00 = bflo(eg[t].x) + zd[t] * (bfhi(eg[t].x) - bflo(eg[t].x));
            const float z01 = bflo(eg[t].y) + zd[t] * (bfhi(eg[t].y) - bflo(eg[t].y));
            const float z10 = bflo(eg[t].z) + zd[t] * (bfhi(eg[t].z) - bflo(eg[t].z));
            const float z11 = bflo(eg[t].w) + zd[t] * (bfhi(eg[t].w) - bflo(eg[t].w));
            const float y0v = z00 + yd[t] * (z01 - z00);
            const float y1v = z10 + yd[t] * (z11 - z10);
            o1[t] = y0v + xd[t] * (y1v - y0v);
        }
        {
            const float z00 = bflo(eb[t].x) + zd[t] * (bfhi(eb[t].x) - bflo(eb[t].x));
            const float z01 = bflo(eb[t].y) + zd[t] * (bfhi(eb[t].y) - bflo(eb[t].y));
            const float z10 = bflo(eb[t].z) + zd[t] * (bfhi(eb[t].z) - bflo(eb[t].z));
            const float z11 = bflo(eb[t].w) + zd[t] * (bfhi(eb[t].w) - bflo(eb[t].w));
            const float y0v = z00 + yd[t] * (z01 - z00);
            const float y1v = z10 + yd[t] * (z11 - z10);
            o2[t] = y0v + xd[t] * (y1v - y0v);
        }
    }
    float4n* ob = (float4n*)(dout + (size_t)b * 3 * NPIX);
    float4n s0; s0.x = o0[0]; s0.y = o0[1]; s0.z = o0[2]; s0.w = o0[3];
    float4n s1; s1.x = o1[0]; s1.y = o1[1]; s1.z = o1[2]; s1.w = o1[3];
    float4n s2; s2.x = o2[0]; s2.y = o2[1]; s2.z = o2[2]; s2.w = o2[3];
    __builtin_nontemporal_store(s0, &ob[q]);
    __builtin_nontemporal_store(s1, &ob[NPIX4 + q]);
    __builtin_nontemporal_store(s2, &ob[2 * NPIX4 + q]);
}

extern "C" void kernel_launch(void* const* d_in, const int* in_sizes, int n_in,
                              void* d_out, int out_size, void* d_ws, size_t ws_size,
                              hipStream_t stream)
{
    const float* img_lr   = (const float*)d_in[0];
    const float* img_full = (const float*)d_in[1];
    const float* bases    = (const float*)d_in[2];
    const float* wp_c1_w  = (const float*)d_in[3];
    const float* wp_c1_b  = (const float*)d_in[4];
    const float* wp_c2_w  = (const float*)d_in[5];
    const float* wp_c2_b  = (const float*)d_in[6];
    const float* wp_fc_w  = (const float*)d_in[7];
    const float* wp_fc_b  = (const float*)d_in[8];
    const float* rp_c1_w  = (const float*)d_in[9];
    const float* rp_c1_b  = (const float*)d_in[10];
    const float* rp_c2_w  = (const float*)d_in[11];
    const float* rp_c2_b  = (const float*)d_in[12];
    const float* fcu_w    = (const float*)d_in[13];
    const float* fcu_b    = (const float*)d_in[14];
    const float* fcv_w    = (const float*)d_in[15];
    const float* fcv_b    = (const float*)d_in[16];
    const float* fcw_w    = (const float*)d_in[17];
    const float* fcw_b    = (const float*)d_in[18];
    const float* fcc_w    = (const float*)d_in[19];
    const float* fcc_b    = (const float*)d_in[20];
    float* ws  = (float*)d_ws;
    float* out = (float*)d_out;

    encoder_kernel<<<dim3(256), 256, 0, stream>>>(
        img_lr, wp_c1_w, wp_c1_b, wp_c2_w, wp_c2_b,
        rp_c1_w, rp_c1_b, rp_c2_w, rp_c2_b, ws);
    lut_kernel<<<dim3(NLUTBLK), 256, 0, stream>>>(
        bases, wp_fc_w, wp_fc_b, fcu_w, fcu_b, fcv_w, fcv_b,
        fcw_w, fcw_b, fcc_w, fcc_b, ws, out);
    apply_kernel<<<dim3(BATCH * NPIX4 / 256), 256, 0, stream>>>(img_full, ws, out);
}

// Round 6
// 364.635 us; speedup vs baseline: 1.2641x; 1.0033x over previous
//
#include <hip/hip_runtime.h>
#include <stdint.h>

// ---------------- problem constants ----------------
#define GN   33
#define GG   1089      // 33*33
#define GGG  35937     // 33^3
#define BATCH 4
#define HFULL 1080
#define WFULL 1920
#define NPIX (HFULL*WFULL)          // 2,073,600 per channel
#define NPIX4 (NPIX/4)              // 518,400 float4 per channel

// d_out layout (floats): out | alpha | delta | L | delta_norm
#define OUT_ALPHA 24883200
#define OUT_DELTA 24883232
#define OUT_L     25314476
#define OUT_DNORM 25745720

// ---------------- workspace layout ----------------
// bytes [0, 9,199,872): 64B-entry packed LUT (4*35937 entries)
#define WS_LUT64B 0
#define WS_PART   2300000   // encoder partials [enc2][b4][tile32][o32]
#define WS_DN     2308192   // 132 per-block |delta| partials
#define NLUTBLK   132       // 4 batches * 33 x-planes

// native clang vectors (required by __builtin_nontemporal_*)
typedef float  float4n __attribute__((ext_vector_type(4)));
typedef unsigned int uint4n __attribute__((ext_vector_type(4)));

__device__ __forceinline__ unsigned short f2bf(float f) {
    unsigned u = __float_as_uint(f);
    unsigned r = (u + 0x7fffu + ((u >> 16) & 1u)) >> 16;
    return (unsigned short)r;
}
__device__ __forceinline__ float bflo(unsigned u) { return __uint_as_float(u << 16); }
__device__ __forceinline__ float bfhi(unsigned u) { return __uint_as_float(u & 0xffff0000u); }

// ---------------- fused encoder: conv1(3->16,s2) + conv2(16->32,s2) + mean partials ----------------
__global__ __launch_bounds__(256) void encoder_kernel(
    const float* __restrict__ img,
    const float* __restrict__ w1wp, const float* __restrict__ b1wp,
    const float* __restrict__ w2wp, const float* __restrict__ b2wp,
    const float* __restrict__ w1rp, const float* __restrict__ b1rp,
    const float* __restrict__ w2rp, const float* __restrict__ b2rp,
    float* __restrict__ ws)
{
    const int bi = blockIdx.x;
    const int enc = bi >> 7, b = (bi >> 5) & 3, rt = (bi >> 1) & 15, ct = bi & 1;
    const float* w1 = enc ? w1rp : w1wp;
    const float* b1 = enc ? b1rp : b1wp;
    const float* w2 = enc ? w2rp : w2wp;
    const float* b2 = enc ? b2rp : b2wp;
    __shared__ float simg[3][19][132];
    __shared__ float sh1[4][9][66];
    __shared__ float red[4][16];
    const float* imb = img + (size_t)b * 3 * 65536;
    const int tid = threadIdx.x;

    for (int l = tid; l < 3 * 19 * 131; l += 256) {
        const int c = l / (19 * 131);
        const int rem = l - c * (19 * 131);
        const int rw = rem / 131, cl = rem - rw * 131;
        const int gr = 16 * rt - 3 + rw, gc = 128 * ct - 3 + cl;
        float v = 0.f;
        if ((unsigned)gr < 256u && (unsigned)gc < 256u)
            v = imb[(c << 16) + (gr << 8) + gc];
        simg[c][rw][cl] = v;
    }
    __syncthreads();

    const int p = tid & 127, h = tid >> 7;
    const int prow = p >> 5, pcol = p & 31;
    float acc[16];
    #pragma unroll
    for (int o = 0; o < 16; ++o) acc[o] = b2[h * 16 + o];

    for (int cc0 = 0; cc0 < 16; cc0 += 4) {
        if (cc0) __syncthreads();
        for (int l = tid; l < 4 * 9 * 65; l += 256) {
            const int oc = l / (9 * 65);
            const int rem = l - oc * (9 * 65);
            const int r = rem / 65, cl = rem - r * 65;
            const int hrow = 8 * rt - 1 + r, hcol = 64 * ct - 1 + cl;
            float v = 0.f;
            if ((unsigned)hrow < 128u && (unsigned)hcol < 128u) {
                float a1 = b1[cc0 + oc];
                const float* wo = w1 + (cc0 + oc) * 27;
                #pragma unroll
                for (int c = 0; c < 3; ++c)
                    #pragma unroll
                    for (int ky = 0; ky < 3; ++ky)
                        #pragma unroll
                        for (int kx = 0; kx < 3; ++kx)
                            a1 += wo[c * 9 + ky * 3 + kx] * simg[c][2 * r + ky][2 * cl + kx];
                v = fmaxf(a1, 0.f);
            }
            sh1[oc][r][cl] = v;
        }
        __syncthreads();
        #pragma unroll
        for (int cc = 0; cc < 4; ++cc) {
            float vv[9];
            #pragma unroll
            for (int ky = 0; ky < 3; ++ky)
                #pragma unroll
                for (int kx = 0; kx < 3; ++kx)
                    vv[ky * 3 + kx] = sh1[cc][2 * prow + ky][2 * pcol + kx];
            #pragma unroll
            for (int o = 0; o < 16; ++o) {
                const float* wo = w2 + (h * 16 + o) * 144 + (cc0 + cc) * 9;
                #pragma unroll
                for (int k = 0; k < 9; ++k) acc[o] += wo[k] * vv[k];
            }
        }
    }
    const int lane = tid & 63, wv = tid >> 6;
    #pragma unroll
    for (int o = 0; o < 16; ++o) {
        float v = fmaxf(acc[o], 0.f);
        #pragma unroll
        for (int off = 32; off; off >>= 1) v += __shfl_down(v, off);
        if (lane == 0) red[wv][o] = v;
    }
    __syncthreads();
    if (tid < 32) {
        const int o = tid & 15, g = tid >> 4;
        const float s = red[g * 2][o] + red[g * 2 + 1][o];
        ws[WS_PART + ((enc * 4 + b) * 32 + (rt * 2 + ct)) * 32 + g * 16 + o] = s;
    }
}

// ---------------- fused heads + plane-pair LUT build + pack ----------------
// block = (b, x-plane). Computes planes x and x+1 ONCE each into LDS
// (2x total redundancy vs 8x per-corner recompute), then packs plane x.
__global__ __launch_bounds__(256) void lut_kernel(
    const float* __restrict__ bases,
    const float* __restrict__ wp_fc_w, const float* __restrict__ wp_fc_b,
    const float* __restrict__ fcu_w, const float* __restrict__ fcu_b,
    const float* __restrict__ fcv_w, const float* __restrict__ fcv_b,
    const float* __restrict__ fcw_w, const float* __restrict__ fcw_b,
    const float* __restrict__ fcc_w, const float* __restrict__ fcc_b,
    float* __restrict__ ws, float* __restrict__ dout)
{
    const int b = blockIdx.x & 3;
    const int x = blockIdx.x >> 2;          // 0..32
    const int x1 = min(x + 1, GN - 1);
    const int tid = threadIdx.x;
    __shared__ float mean[2][32];
    __shared__ float U[264], V[264], W[264], Cc[24], Al[8];
    __shared__ float Lp[2][GG * 3];         // 26.1 KB: L for planes x, x1

    // phase 1a: reduce encoder partials
    if (tid < 64) {
        const int enc = tid >> 5, o = tid & 31;
        const float* pp = ws + WS_PART + (enc * 4 + b) * 1024 + o;
        float s = 0.f;
        #pragma unroll
        for (int i = 0; i < 32; ++i) s += pp[i * 32];
        mean[enc][o] = s * (1.f / 4096.f);
    }
    __syncthreads();
    // phase 1b: FC heads (redundant per block, trivial)
    for (int r = tid; r < 824; r += 256) {
        if (r < 8) {
            const float* row = wp_fc_w + r * 32;
            float a = wp_fc_b[r];
            #pragma unroll 8
            for (int q = 0; q < 32; ++q) a += row[q] * mean[0][q];
            Al[r] = a;
            dout[OUT_ALPHA + b * 8 + r] = a;
        } else if (r < 272) {
            const int jj = r - 8;
            const float* row = fcu_w + jj * 32;
            float a = fcu_b[jj];
            #pragma unroll 8
            for (int q = 0; q < 32; ++q) a += row[q] * mean[1][q];
            U[jj] = a;
        } else if (r < 536) {
            const int jj = r - 272;
            const float* row = fcv_w + jj * 32;
            float a = fcv_b[jj];
            #pragma unroll 8
            for (int q = 0; q < 32; ++q) a += row[q] * mean[1][q];
            V[jj] = a;
        } else if (r < 800) {
            const int jj = r - 536;
            const float* row = fcw_w + jj * 32;
            float a = fcw_b[jj];
            #pragma unroll 8
            for (int q = 0; q < 32; ++q) a += row[q] * mean[1][q];
            W[jj] = a;
        } else {
            const int jj = r - 800;
            const float* row = fcc_w + jj * 32;
            float a = fcc_b[jj];
            #pragma unroll 8
            for (int q = 0; q < 32; ++q) a += row[q] * mean[1][q];
            Cc[jj] = a;
        }
    }
    __syncthreads();

    float ux0[8], ux1[8], cr[8][3];
    #pragma unroll
    for (int r = 0; r < 8; ++r) {
        ux0[r] = U[r * GN + x];
        ux1[r] = U[r * GN + x1];
        cr[r][0] = Cc[r * 3 + 0];
        cr[r][1] = Cc[r * 3 + 1];
        cr[r][2] = Cc[r * 3 + 2];
    }

    // phase 2: compute L for both planes, coalesced bases reads
    float sum3 = 0.f;
    #pragma unroll
    for (int px = 0; px < 2; ++px) {
        const int xi = px ? x1 : x;
        for (int i = tid; i < GG; i += 256) {
            const int y = i / GN, z = i - y * GN;
            float d0 = 0.f, d1 = 0.f, d2 = 0.f;
            #pragma unroll
            for (int r = 0; r < 8; ++r) {
                const float t = (px ? ux1[r] : ux0[r]) * V[r * GN + y] * W[r * GN + z];
                d0 += t * cr[r][0];
                d1 += t * cr[r][1];
                d2 += t * cr[r][2];
            }
            float l0 = d0, l1 = d1, l2 = d2;
            const float* bp = bases + (size_t)(xi * GG + i) * 3;
            #pragma unroll
            for (int k = 0; k < 8; ++k) {
                const float a = Al[k];
                const float* bk = bp + (size_t)k * GGG * 3;
                l0 += a * bk[0];
                l1 += a * bk[1];
                l2 += a * bk[2];
            }
            Lp[px][i * 3 + 0] = l0;
            Lp[px][i * 3 + 1] = l1;
            Lp[px][i * 3 + 2] = l2;
            if (px == 0) {
                const size_t o3 = ((size_t)b * GGG + x * GG + i) * 3;
                dout[OUT_DELTA + o3 + 0] = d0;
                dout[OUT_DELTA + o3 + 1] = d1;
                dout[OUT_DELTA + o3 + 2] = d2;
                dout[OUT_L + o3 + 0] = l0;
                dout[OUT_L + o3 + 1] = l1;
                dout[OUT_L + o3 + 2] = l2;
                sum3 += fabsf(d0) + fabsf(d1) + fabsf(d2);
            }
        }
    }
    __syncthreads();

    // phase 3: pack entries for plane x from LDS
    for (int i = tid; i < GG; i += 256) {
        const int y = i / GN, z = i - y * GN;
        const int y1 = min(y + 1, GN - 1), z1 = min(z + 1, GN - 1);
        const int i00 = (y  * GN + z ) * 3, i01 = (y  * GN + z1) * 3;
        const int i10 = (y1 * GN + z ) * 3, i11 = (y1 * GN + z1) * 3;
        uint4 wr, wg, wb;
        #pragma unroll
        for (int c = 0; c < 3; ++c) {
            const unsigned w00 = (unsigned)f2bf(Lp[0][i00 + c]) | ((unsigned)f2bf(Lp[0][i01 + c]) << 16);
            const unsigned w01 = (unsigned)f2bf(Lp[0][i10 + c]) | ((unsigned)f2bf(Lp[0][i11 + c]) << 16);
            const unsigned w10 = (unsigned)f2bf(Lp[1][i00 + c]) | ((unsigned)f2bf(Lp[1][i01 + c]) << 16);
            const unsigned w11 = (unsigned)f2bf(Lp[1][i10 + c]) | ((unsigned)f2bf(Lp[1][i11 + c]) << 16);
            uint4& wv = c == 0 ? wr : (c == 1 ? wg : wb);
            wv.x = w00; wv.y = w01; wv.z = w10; wv.w = w11;
        }
        uint4* dst = (uint4*)((char*)ws + WS_LUT64B) + ((size_t)b * GGG + x * GG + i) * 4;
        dst[0] = wr; dst[1] = wg; dst[2] = wb;
    }

    // per-block |delta| partial
    #pragma unroll
    for (int off = 32; off; off >>= 1) sum3 += __shfl_down(sum3, off);
    __shared__ float s4[4];
    const int lane = tid & 63, wid = tid >> 6;
    if (!lane) s4[wid] = sum3;
    __syncthreads();
    if (!tid) ws[WS_DN + blockIdx.x] = s4[0] + s4[1] + s4[2] + s4[3];
}

// ---------------- trilinear apply (+ dnorm finish in block 0) ----------------
// NT loads/stores on the img/out streams keep the 2.3 MB/XCD LUT resident in L2.
__global__ __launch_bounds__(256) void apply_kernel(
    const float* __restrict__ img,
    const float* __restrict__ ws, float* __restrict__ dout)
{
    if (blockIdx.x == 0 && threadIdx.x < 64) {
        float s = 0.f;
        for (int i = threadIdx.x; i < NLUTBLK; i += 64) s += ws[WS_DN + i];
        #pragma unroll
        for (int off = 32; off; off >>= 1) s += __shfl_down(s, off);
        if (threadIdx.x == 0)
            dout[OUT_DNORM] = s * (1.0f / (float)(BATCH * GGG * 3));
    }
    const int b = blockIdx.x & 3;     // with round-robin block->XCD, XCD j sees only batch j&3
    const int q = (blockIdx.x >> 2) * 256 + threadIdx.x;
    const float4n* base = (const float4n*)(img + (size_t)b * 3 * NPIX);
    const float4n rv = __builtin_nontemporal_load(&base[q]);
    const float4n gv = __builtin_nontemporal_load(&base[NPIX4 + q]);
    const float4n bv = __builtin_nontemporal_load(&base[2 * NPIX4 + q]);
    const uint4* lut = (const uint4*)((const char*)ws + WS_LUT64B) + (size_t)b * GGG * 4;

    float rrr[4] = {rv.x, rv.y, rv.z, rv.w};
    float ggg[4] = {gv.x, gv.y, gv.z, gv.w};
    float bbb[4] = {bv.x, bv.y, bv.z, bv.w};
    int idx[4]; float xd[4], yd[4], zd[4];
    #pragma unroll
    for (int t = 0; t < 4; ++t) {
        const float xf = fminf(fmaxf(rrr[t] * 32.f, 0.f), 31.999998f);
        const float yf = fminf(fmaxf(ggg[t] * 32.f, 0.f), 31.999998f);
        const float zf = fminf(fmaxf(bbb[t] * 32.f, 0.f), 31.999998f);
        const int x0 = (int)xf, y0 = (int)yf, z0 = (int)zf;
        xd[t] = xf - (float)x0; yd[t] = yf - (float)y0; zd[t] = zf - (float)z0;
        idx[t] = (x0 * GN + y0) * GN + z0;
    }
    uint4 er[4], eg[4], eb[4];
    #pragma unroll
    for (int t = 0; t < 4; ++t) {
        const uint4* e = lut + (size_t)idx[t] * 4;
        er[t] = e[0]; eg[t] = e[1]; eb[t] = e[2];
    }
    float o0[4], o1[4], o2[4];
    #pragma unroll
    for (int t = 0; t < 4; ++t) {
        {
            const float z00 = bflo(er[t].x) + zd[t] * (bfhi(er[t].x) - bflo(er[t].x));
            const float z01 = bflo(er[t].y) + zd[t] * (bfhi(er[t].y) - bflo(er[t].y));
            const float z10 = bflo(er[t].z) + zd[t] * (bfhi(er[t].z) - bflo(er[t].z));
            const float z11 = bflo(er[t].w) + zd[t] * (bfhi(er[t].w) - bflo(er[t].w));
            const float y0v = z00 + yd[t] * (z01 - z00);
            const float y1v = z10 + yd[t] * (z11 - z10);
            o0[t] = y0v + xd[t] * (y1v - y0v);
        }
        {
            const float z00 = bflo(eg[t].x) + zd[t] * (bfhi(eg[t].x) - bflo(eg[t].x));
            const float z01 = bflo(eg[t].y) + zd[t] * (bfhi(eg[t].y) - bflo(eg[t].y));
            const float z10 = bflo(eg[t].z) + zd[t] * (bfhi(eg[t].z) - bflo(eg[t].z));
            const float z11 = bflo(eg[t].w) + zd[t] * (bfhi(eg[t].w) - bflo(eg[t].w));
            const float y0v = z00 + yd[t] * (z01 - z00);
            const float y1v = z10 + yd[t] * (z11 - z10);
            o1[t] = y0v + xd[t] * (y1v - y0v);
        }
        {
            const float z00 = bflo(eb[t].x) + zd[t] * (bfhi(eb[t].x) - bflo(eb[t].x));
            const float z01 = bflo(eb[t].y) + zd[t] * (bfhi(eb[t].y) - bflo(eb[t].y));
            const float z10 = bflo(eb[t].z) + zd[t] * (bfhi(eb[t].z) - bflo(eb[t].z));
            const float z11 = bflo(eb[t].w) + zd[t] * (bfhi(eb[t].w) - bflo(eb[t].w));
            const float y0v = z00 + yd[t] * (z01 - z00);
            const float y1v = z10 + yd[t] * (z11 - z10);
            o2[t] = y0v + xd[t] * (y1v - y0v);
        }
    }
    float4n* ob = (float4n*)(dout + (size_t)b * 3 * NPIX);
    float4n s0; s0.x = o0[0]; s0.y = o0[1]; s0.z = o0[2]; s0.w = o0[3];
    float4n s1; s1.x = o1[0]; s1.y = o1[1]; s1.z = o1[2]; s1.w = o1[3];
    float4n s2; s2.x = o2[0]; s2.y = o2[1]; s2.z = o2[2]; s2.w = o2[3];
    __builtin_nontemporal_store(s0, &ob[q]);
    __builtin_nontemporal_store(s1, &ob[NPIX4 + q]);
    __builtin_nontemporal_store(s2, &ob[2 * NPIX4 + q]);
}

extern "C" void kernel_launch(void* const* d_in, const int* in_sizes, int n_in,
                              void* d_out, int out_size, void* d_ws, size_t ws_size,
                              hipStream_t stream)
{
    const float* img_lr   = (const float*)d_in[0];
    const float* img_full = (const float*)d_in[1];
    const float* bases    = (const float*)d_in[2];
    const float* wp_c1_w  = (const float*)d_in[3];
    const float* wp_c1_b  = (const float*)d_in[4];
    const float* wp_c2_w  = (const float*)d_in[5];
    const float* wp_c2_b  = (const float*)d_in[6];
    const float* wp_fc_w  = (const float*)d_in[7];
    const float* wp_fc_b  = (const float*)d_in[8];
    const float* rp_c1_w  = (const float*)d_in[9];
    const float* rp_c1_b  = (const float*)d_in[10];
    const float* rp_c2_w  = (const float*)d_in[11];
    const float* rp_c2_b  = (const float*)d_in[12];
    const float* fcu_w    = (const float*)d_in[13];
    const float* fcu_b    = (const float*)d_in[14];
    const float* fcv_w    = (const float*)d_in[15];
    const float* fcv_b    = (const float*)d_in[16];
    const float* fcw_w    = (const float*)d_in[17];
    const float* fcw_b    = (const float*)d_in[18];
    const float* fcc_w    = (const float*)d_in[19];
    const float* fcc_b    = (const float*)d_in[20];
    float* ws  = (float*)d_ws;
    float* out = (float*)d_out;

    encoder_kernel<<<dim3(256), 256, 0, stream>>>(
        img_lr, wp_c1_w, wp_c1_b, wp_c2_w, wp_c2_b,
        rp_c1_w, rp_c1_b, rp_c2_w, rp_c2_b, ws);
    lut_kernel<<<dim3(NLUTBLK), 256, 0, stream>>>(
        bases, wp_fc_w, wp_fc_b, fcu_w, fcu_b, fcv_w, fcv_b,
        fcw_w, fcw_b, fcc_w, fcc_b, ws, out);
    apply_kernel<<<dim3(BATCH * NPIX4 / 256), 256, 0, stream>>>(img_full, ws, out);
}